// Round 5
// baseline (503.177 us; speedup 1.0000x reference)
//
#include <hip/hip_runtime.h>
#include <hip/hip_fp16.h>

// SJLT projection: out[b, idx[d,j]] += x[b,d]*sgn[d,j]; out *= 1/sqrt(8)
// B=32, D=1e6, P=4096, c=8.
//
// R4 post-mortem: split passes were bound by a ~300-cyc dependent DS chain
// per rank call (ds_add_rtn_u32 ~120cyc -> bpermute -> ds_write) at 8-12
// waves/CU. R5: ranking fully in VGPRs — lane L keeps the running count of
// bin L (ballot masks are wave-uniform, so lane L recomputes bin-L's peer
// mask in VALU). Wave-private stage regions (no cross-wave races), one
// pipelined bpermute + one ds_write per 64 entries. Gather stages its
// bucket list in LDS to shorten the global dependency chain.

#define D_TOTAL 1000000
#define PROJ    4096
#define C_SK    8
#define NE      (D_TOTAL * C_SK)     // 8,000,000 entries
#define SCALE   0.35355339059327373f

#define CAPA    131072               // per coarse-partition cap
#define CAP     2304                 // per fine-bucket cap (mu+7.9sig)
#define WCAP    64                   // per-wave per-bin LDS cap (mu=32,+5.7sig)
#define TILE    8192                 // entries per block in split passes

// ws layout
#define CURA_OFF   0                 // 64 ints
#define CURB_OFF   16384             // 4096 ints
#define LISTB_OFF  65536
#define LISTB_SZ   ((size_t)PROJ * CAP * 4)            // 37,748,736
#define SHARED_OFF (LISTB_OFF + LISTB_SZ)              // 37,814,272
#define XT_SZ      ((size_t)D_TOTAL * 32 * 2)          // 64,000,000
#define WS_NEEDED  (SHARED_OFF + XT_SZ)                // ~102 MB (xT overlays listA)

// ---------------- K0: init cursors ----------------
__global__ void init_cursors_kernel(int* __restrict__ curA, int* __restrict__ curB) {
    int i = blockIdx.x * blockDim.x + threadIdx.x;
    if (i < 64)   curA[i] = i * CAPA;
    if (i < PROJ) curB[i] = i * CAP;
}

// VGPR-counter multisplit rank+stage. All 64 lanes must reach this call;
// `ok` masks tail lanes (invalid lanes must pass kb=0). kb in [0,64).
// cnt_lane: running count of bin==lane for THIS wave (VGPR).
__device__ __forceinline__ void rank_stage_wp(bool ok, int kb, int payload,
                                              int& cnt_lane,
                                              int* __restrict__ stageW,
                                              int* __restrict__ gcur,
                                              int* __restrict__ glist,
                                              int gidx_base, int capPer) {
    const int lane = threadIdx.x & 63;
    const unsigned long long valid = __ballot(ok);
    const unsigned long long v0 = __ballot(kb & 1);
    const unsigned long long v1 = __ballot(kb & 2);
    const unsigned long long v2 = __ballot(kb & 4);
    const unsigned long long v3 = __ballot(kb & 8);
    const unsigned long long v4 = __ballot(kb & 16);
    const unsigned long long v5 = __ballot(kb & 32);
    // peers sharing MY entry's bin
    unsigned long long me = valid;
    me &= (kb & 1)  ? v0 : ~v0;
    me &= (kb & 2)  ? v1 : ~v1;
    me &= (kb & 4)  ? v2 : ~v2;
    me &= (kb & 8)  ? v3 : ~v3;
    me &= (kb & 16) ? v4 : ~v4;
    me &= (kb & 32) ? v5 : ~v5;
    // entries whose bin == my LANE id (for the running counter)
    unsigned long long bl = valid;
    bl &= (lane & 1)  ? v0 : ~v0;
    bl &= (lane & 2)  ? v1 : ~v1;
    bl &= (lane & 4)  ? v2 : ~v2;
    bl &= (lane & 8)  ? v3 : ~v3;
    bl &= (lane & 16) ? v4 : ~v4;
    bl &= (lane & 32) ? v5 : ~v5;
    const int rank = __popcll(me & ((1ULL << lane) - 1ULL));
    const int base = __shfl(cnt_lane, kb, 64);        // one pipelined bpermute
    const int pos  = base + rank;
    if (ok) {
        if (pos < WCAP) {
            stageW[kb * WCAP + pos] = payload;
        } else {                                      // rare overflow
            const int gp = atomicAdd(&gcur[gidx_base + kb], 1);
            if (gp < (gidx_base + kb + 1) * capPer) glist[gp] = payload;
        }
    }
    cnt_lane += __popcll(bl);
}

// flush wave-private regions: one global reservation per bin, wave-parallel copy
__device__ __forceinline__ void flush_wp(int cnt_lane,
                                         int* __restrict__ cntS, int* __restrict__ baseS,
                                         const int* __restrict__ stage,
                                         int* __restrict__ gcur, int* __restrict__ glist,
                                         int gidx_base, int capPer) {
    const int tid = threadIdx.x;
    const int w = tid >> 6, lane = tid & 63;
    cntS[w * 64 + lane] = min(cnt_lane, WCAP);
    __syncthreads();
    if (tid < 64) {
        const int m0 = cntS[0 * 64 + tid], m1 = cntS[1 * 64 + tid];
        const int m2 = cntS[2 * 64 + tid], m3 = cntS[3 * 64 + tid];
        const int g  = atomicAdd(&gcur[gidx_base + tid], m0 + m1 + m2 + m3);
        baseS[0 * 64 + tid] = g;
        baseS[1 * 64 + tid] = g + m0;
        baseS[2 * 64 + tid] = g + m0 + m1;
        baseS[3 * 64 + tid] = g + m0 + m1 + m2;
    }
    __syncthreads();
    const int* stW = stage + w * 64 * WCAP;
    #pragma unroll 1
    for (int bin = 0; bin < 64; ++bin) {
        const int m   = cntS[w * 64 + bin];
        const int gb  = baseS[w * 64 + bin];
        const int lim = (gidx_base + bin + 1) * capPer;
        for (int i = lane; i < m; i += 64)
            if (gb + i < lim) glist[gb + i] = stW[bin * WCAP + i];
    }
}

// ---------------- KA: coarse split (bucket>>6) ----------------
// grid 977 x 256; payload {sign:31, low6:24..29, g:0..22}
__global__ __launch_bounds__(256, 2)
void pass_a_kernel(const int* __restrict__ idx, const int* __restrict__ sgn,
                   int* __restrict__ curA, int* __restrict__ listA) {
    __shared__ int stage[4 * 64 * WCAP];   // 65,536 B
    __shared__ int cntS[256];
    __shared__ int baseS[256];
    const int tid = threadIdx.x;
    int* stW = stage + (tid >> 6) * 64 * WCAP;
    int cnt_lane = 0;

    const int v0 = blockIdx.x * (TILE / 4);
    #pragma unroll 1
    for (int k = 0; k < 8; ++k) {
        const int vi = v0 + k * 256 + tid;
        const bool okv = vi < NE / 4;
        int4 i4 = {0,0,0,0}, s4 = {0,0,0,0};
        if (okv) { i4 = ((const int4*)idx)[vi]; s4 = ((const int4*)sgn)[vi]; }
        const int g0 = vi * 4;
        #pragma unroll
        for (int m = 0; m < 4; ++m) {
            const int bucket = (m == 0) ? i4.x : (m == 1) ? i4.y : (m == 2) ? i4.z : i4.w;
            const int sg     = (m == 0) ? s4.x : (m == 1) ? s4.y : (m == 2) ? s4.z : s4.w;
            const int kb = okv ? (bucket >> 6) : 0;
            const int payload = (g0 + m) | ((bucket & 63) << 24)
                              | (int)((unsigned)sg & 0x80000000u);
            rank_stage_wp(okv, kb, payload, cnt_lane, stW, curA, listA, 0, CAPA);
        }
    }
    __syncthreads();
    flush_wp(cnt_lane, cntS, baseS, stage, curA, listA, 0, CAPA);
}

// ---------------- KB: fine split (bucket&63) ----------------
// grid 1024 = 64 parts x 16 tiles of 8192
__global__ __launch_bounds__(256, 2)
void pass_b_kernel(const int* __restrict__ curA, const int* __restrict__ listA,
                   int* __restrict__ curB, int* __restrict__ listB) {
    __shared__ int stage[4 * 64 * WCAP];
    __shared__ int cntS[256];
    __shared__ int baseS[256];
    const int tid  = threadIdx.x;
    const int part = blockIdx.x >> 4;
    const int tile = blockIdx.x & 15;
    int* stW = stage + (tid >> 6) * 64 * WCAP;
    int cnt_lane = 0;

    const int pstart = part * CAPA;
    const int pcount = min(curA[part] - pstart, CAPA);
    const int t0 = tile * TILE;
    const int t1 = min(t0 + TILE, pcount);

    #pragma unroll 1
    for (int k = 0; k < TILE / 256; ++k) {
        const int i  = t0 + k * 256 + tid;
        const bool ok = i < t1;
        const int e  = ok ? listA[pstart + i] : 0;
        const int kb = ok ? ((e >> 24) & 63) : 0;
        const int payload = e & 0x807FFFFF;          // keep sign + g
        rank_stage_wp(ok, kb, payload, cnt_lane, stW, curB, listB, part * 64, CAP);
    }
    __syncthreads();
    flush_wp(cnt_lane, cntS, baseS, stage, curB, listB, part * 64, CAP);
}

// ---------------- K4: transpose x[32][1e6] -> x_T[1e6][32] fp16 ----------------
__global__ __launch_bounds__(256, 4)
void transpose_kernel(const float* __restrict__ x, unsigned short* __restrict__ xT) {
    __shared__ float tile[32][257];
    const int tid = threadIdx.x;
    const int d0  = blockIdx.x * 256;
    const int row = tid >> 3;
    const int c8  = tid & 7;

    if (d0 + 256 <= D_TOTAL) {
        #pragma unroll
        for (int k = 0; k < 8; ++k) {
            const int c = (c8 + 8 * k) * 4;
            const float4 v = *(const float4*)(x + (size_t)row * D_TOTAL + d0 + c);
            tile[row][c] = v.x; tile[row][c+1] = v.y;
            tile[row][c+2] = v.z; tile[row][c+3] = v.w;
        }
    } else {
        for (int k = 0; k < 8; ++k) {
            const int c = (c8 + 8 * k) * 4;
            for (int m = 0; m < 4; ++m) {
                const int d = d0 + c + m;
                tile[row][c + m] = (d < D_TOTAL) ? x[(size_t)row * D_TOTAL + d] : 0.f;
            }
        }
    }
    __syncthreads();

    const int part = tid & 3;
    #pragma unroll
    for (int k = 0; k < 4; ++k) {
        const int dl = k * 64 + (tid >> 2);
        if (d0 + dl < D_TOTAL) {
            unsigned short h[8];
            #pragma unroll
            for (int i = 0; i < 8; ++i)
                h[i] = __half_as_ushort(__float2half(tile[part * 8 + i][dl]));
            *(uint4*)(xT + ((size_t)(d0 + dl)) * 32 + part * 8) = *(const uint4*)h;
        }
    }
}

// ---------------- K5: gather — LDS-staged list, 16 slots x 4 lanes x 16B ----------------
__global__ __launch_bounds__(256, 8)
void gather_kernel(const int* __restrict__ curB, const int* __restrict__ listB,
                   const unsigned short* __restrict__ xT, float* __restrict__ out) {
    __shared__ int   lst[CAP];             // 9,216 B
    __shared__ float red[4][32];
    const int tid  = threadIdx.x;
    const int w    = tid >> 6;
    const int lane = tid & 63;
    const int p    = blockIdx.x;
    const int start = p * CAP;
    const int n     = min(curB[p] - start, CAP);
    const int slot = lane >> 2;
    const int bq   = lane & 3;

    for (int i = tid; i < n; i += 256)
        lst[i] = __builtin_nontemporal_load(listB + start + i);
    __syncthreads();

    float a0=0.f,a1=0.f,a2=0.f,a3=0.f,a4=0.f,a5=0.f,a6=0.f,a7=0.f;
    #pragma unroll 4
    for (int i0 = w * 16; i0 < n; i0 += 64) {
        const int  e  = i0 + slot;
        const bool ok = e < n;
        const int  pl = lst[ok ? e : 0];
        const int  d  = ok ? ((pl & 0x7FFFFF) >> 3) : 0;
        const float s = ok ? ((pl < 0) ? -1.f : 1.f) : 0.f;
        const uint4 hv = *(const uint4*)(xT + (size_t)d * 32 + bq * 8);
        float2 f;
        f = __half22float2(*(const __half2*)&hv.x); a0 = fmaf(s, f.x, a0); a1 = fmaf(s, f.y, a1);
        f = __half22float2(*(const __half2*)&hv.y); a2 = fmaf(s, f.x, a2); a3 = fmaf(s, f.y, a3);
        f = __half22float2(*(const __half2*)&hv.z); a4 = fmaf(s, f.x, a4); a5 = fmaf(s, f.y, a5);
        f = __half22float2(*(const __half2*)&hv.w); a6 = fmaf(s, f.x, a6); a7 = fmaf(s, f.y, a7);
    }
    #pragma unroll
    for (int m = 4; m <= 32; m <<= 1) {
        a0 += __shfl_xor(a0, m, 64); a1 += __shfl_xor(a1, m, 64);
        a2 += __shfl_xor(a2, m, 64); a3 += __shfl_xor(a3, m, 64);
        a4 += __shfl_xor(a4, m, 64); a5 += __shfl_xor(a5, m, 64);
        a6 += __shfl_xor(a6, m, 64); a7 += __shfl_xor(a7, m, 64);
    }
    if (lane < 4) {
        float* r = &red[w][lane * 8];
        r[0]=a0; r[1]=a1; r[2]=a2; r[3]=a3; r[4]=a4; r[5]=a5; r[6]=a6; r[7]=a7;
    }
    __syncthreads();
    if (tid < 32) {
        const float v = red[0][tid] + red[1][tid] + red[2][tid] + red[3][tid];
        out[(size_t)tid * PROJ + p] = v * SCALE;
    }
}

// ---------------- fallback (R1 kernel) if ws too small ----------------
#define BG 8
#define NCHUNK 64
#define BLOCK 1024
__global__ __launch_bounds__(BLOCK, 4)
void sjlt_scatter_fallback(const float* __restrict__ x,
                           const int* __restrict__ idx,
                           const int* __restrict__ sgn,
                           float* __restrict__ out) {
    __shared__ float acc[BG * PROJ];
    const int tid = threadIdx.x;
    #pragma unroll
    for (int i = 0; i < (BG * PROJ) / BLOCK; ++i) acc[i * BLOCK + tid] = 0.0f;
    __syncthreads();
    const int chunk = D_TOTAL / NCHUNK;
    const int d0 = blockIdx.x * chunk;
    const int d1 = d0 + chunk;
    const int bg = blockIdx.y * BG;
    for (int d = d0 + tid; d < d1; d += BLOCK) {
        const int4 i0 = *(const int4*)(idx + (size_t)d * C_SK);
        const int4 i1 = *(const int4*)(idx + (size_t)d * C_SK + 4);
        const int4 s0 = *(const int4*)(sgn + (size_t)d * C_SK);
        const int4 s1 = *(const int4*)(sgn + (size_t)d * C_SK + 4);
        #pragma unroll
        for (int b = 0; b < BG; ++b) {
            const float xv = __builtin_nontemporal_load(x + (size_t)(bg + b) * D_TOTAL + d);
            const unsigned xb = __float_as_uint(xv);
            float* accb = acc + b * PROJ;
            atomicAdd(accb + i0.x, __uint_as_float(xb ^ ((unsigned)s0.x & 0x80000000u)));
            atomicAdd(accb + i0.y, __uint_as_float(xb ^ ((unsigned)s0.y & 0x80000000u)));
            atomicAdd(accb + i0.z, __uint_as_float(xb ^ ((unsigned)s0.z & 0x80000000u)));
            atomicAdd(accb + i0.w, __uint_as_float(xb ^ ((unsigned)s0.w & 0x80000000u)));
            atomicAdd(accb + i1.x, __uint_as_float(xb ^ ((unsigned)s1.x & 0x80000000u)));
            atomicAdd(accb + i1.y, __uint_as_float(xb ^ ((unsigned)s1.y & 0x80000000u)));
            atomicAdd(accb + i1.z, __uint_as_float(xb ^ ((unsigned)s1.z & 0x80000000u)));
            atomicAdd(accb + i1.w, __uint_as_float(xb ^ ((unsigned)s1.w & 0x80000000u)));
        }
    }
    __syncthreads();
    #pragma unroll
    for (int i = 0; i < (BG * PROJ) / BLOCK; ++i) {
        const int lin = i * BLOCK + tid;
        const int b = lin >> 12;
        const int pp = lin & (PROJ - 1);
        unsafeAtomicAdd(out + (size_t)(bg + b) * PROJ + pp, acc[lin] * SCALE);
    }
}

extern "C" void kernel_launch(void* const* d_in, const int* in_sizes, int n_in,
                              void* d_out, int out_size, void* d_ws, size_t ws_size,
                              hipStream_t stream) {
    const float* x   = (const float*)d_in[0];
    const int*   idx = (const int*)d_in[1];
    const int*   sgn = (const int*)d_in[2];
    float*       out = (float*)d_out;

    if (ws_size < WS_NEEDED) {
        hipMemsetAsync(out, 0, (size_t)out_size * sizeof(float), stream);
        dim3 grid(NCHUNK, 32 / BG);
        sjlt_scatter_fallback<<<grid, BLOCK, 0, stream>>>(x, idx, sgn, out);
        return;
    }

    char* ws = (char*)d_ws;
    int*            curA  = (int*)(ws + CURA_OFF);
    int*            curB  = (int*)(ws + CURB_OFF);
    int*            listB = (int*)(ws + LISTB_OFF);
    int*            listA = (int*)(ws + SHARED_OFF);
    unsigned short* xT    = (unsigned short*)(ws + SHARED_OFF);  // overlays listA

    init_cursors_kernel<<<(PROJ + 255) / 256, 256, 0, stream>>>(curA, curB);
    pass_a_kernel<<<(NE + TILE - 1) / TILE, 256, 0, stream>>>(idx, sgn, curA, listA);
    pass_b_kernel<<<64 * 16, 256, 0, stream>>>(curA, listA, curB, listB);
    transpose_kernel<<<(D_TOTAL + 255) / 256, 256, 0, stream>>>(x, xT);  // clobbers listA (dead)
    gather_kernel<<<PROJ, 256, 0, stream>>>(curB, listB, xT, out);
    // out fully overwritten by gather -> no memset needed
}

// Round 7
// 448.169 us; speedup vs baseline: 1.1227x; 1.1227x over previous
//
#include <hip/hip_runtime.h>
#include <hip/hip_fp16.h>

// SJLT projection: out[b, idx[d,j]] += x[b,d]*sgn[d,j]; out *= 1/sqrt(8)
// B=32, D=1e6, P=4096, c=8.
//
// R5 post-mortem: VGPR-counter ranking regressed prep (2 blocks/CU + heavy
// 64-bit mask VALU). Fixed ~163us harness overhead identified (R1 calib).
// R6: (a) prep reverts to R4 leader-atomic ranking with TILE=4096/BINCAP=112
// -> 29 KB LDS -> 5 blocks/CU for latency hiding; (b) gather uses an 8-deep
// software pipeline (batch payload reads, then 8 independent 16B xT loads)
// to attack the L3 random-line latency bound (3.3 TB/s observed).
// R6b: fix compile — __builtin_nontemporal_load can't take int4*; use plain
// vector load for the LDS staging copy.

#define D_TOTAL 1000000
#define PROJ    4096
#define C_SK    8
#define NE      (D_TOTAL * C_SK)     // 8,000,000 entries
#define SCALE   0.35355339059327373f

#define CAPA    131072               // per coarse-partition cap (mu+17sig)
#define CAP     2304                 // per fine-bucket cap (mu+7.9sig)
#define BINCAP  112                  // per-tile per-bin LDS cap (mu=64,+6sig)
#define TILE    4096                 // entries per block in split passes

// ws layout
#define CURA_OFF   0                 // 64 ints
#define CURB_OFF   16384             // 4096 ints
#define LISTB_OFF  65536
#define LISTB_SZ   ((size_t)PROJ * CAP * 4)            // 37,748,736
#define SHARED_OFF (LISTB_OFF + LISTB_SZ)              // 37,814,272
#define XT_SZ      ((size_t)D_TOTAL * 32 * 2)          // 64,000,000
#define WS_NEEDED  (SHARED_OFF + XT_SZ)                // ~102 MB (xT overlays listA)

// ---------------- K0: init cursors ----------------
__global__ void init_cursors_kernel(int* __restrict__ curA, int* __restrict__ curB) {
    int i = blockIdx.x * blockDim.x + threadIdx.x;
    if (i < 64)   curA[i] = i * CAPA;
    if (i < PROJ) curB[i] = i * CAP;
}

// R4-style ballot rank: leader lane does one LDS atomic per bin-group.
// All 64 lanes must reach this call; `ok` masks tail lanes. kb in [0,64).
__device__ __forceinline__ void rank_and_stage(bool ok, int kb, int payload,
                                               int* __restrict__ cnt,
                                               int* __restrict__ stage,
                                               int* __restrict__ gcur,
                                               int* __restrict__ glist,
                                               int gcur_idx, int glim) {
    const unsigned long long valid = __ballot(ok);
    unsigned long long mask = valid;
    #pragma unroll
    for (int b = 0; b < 6; ++b) {
        const unsigned long long vote = __ballot((kb >> b) & 1);
        mask &= ((kb >> b) & 1) ? vote : ~vote;
    }
    if (ok) {
        const int lane = threadIdx.x & 63;
        const int rank = __popcll(mask & ((1ULL << lane) - 1ULL));
        const int leader = __ffsll((unsigned long long)mask) - 1;
        int base = 0;
        if (rank == 0) base = atomicAdd(&cnt[kb], __popcll(mask));
        base = __shfl(base, leader, 64);
        const int pos = base + rank;
        if (pos < BINCAP) {
            stage[kb * BINCAP + pos] = payload;
        } else {                       // rare overflow: direct global placement
            const int gp = atomicAdd(&gcur[gcur_idx], 1);
            if (gp < glim) glist[gp] = payload;
        }
    }
}

// flush: reserve global space per bin, copy wave-parallel (16 bins/wave)
__device__ __forceinline__ void flush_bins(int* __restrict__ cnt,
                                           int* __restrict__ basek,
                                           const int* __restrict__ stage,
                                           int* __restrict__ gcur,
                                           int* __restrict__ glist,
                                           int gidx0, int capPer) {
    const int tid = threadIdx.x;
    if (tid < 64) {
        const int m = min(cnt[tid], BINCAP);
        cnt[tid]   = m;
        basek[tid] = atomicAdd(&gcur[gidx0 + tid], m);
    }
    __syncthreads();
    const int w = tid >> 6, lane = tid & 63;
    #pragma unroll 1
    for (int bi = 0; bi < 16; ++bi) {
        const int kb  = w * 16 + bi;
        const int m   = cnt[kb];
        const int gb  = basek[kb];
        const int lim = (gidx0 + kb + 1) * capPer;
        for (int i = lane; i < m; i += 64)
            if (gb + i < lim) glist[gb + i] = stage[kb * BINCAP + i];
    }
}

// ---------------- KA: coarse split (bucket>>6) ----------------
// grid 1954 x 256; tile = 4096 entries; payload {sign:31, low6:24..29, g:0..22}
__global__ __launch_bounds__(256, 5)
void pass_a_kernel(const int* __restrict__ idx, const int* __restrict__ sgn,
                   int* __restrict__ curA, int* __restrict__ listA) {
    __shared__ int stage[64 * BINCAP];       // 28,672 B
    __shared__ int cnt[64];
    __shared__ int basek[64];
    const int tid = threadIdx.x;
    if (tid < 64) cnt[tid] = 0;
    __syncthreads();

    const int v0 = blockIdx.x * (TILE / 4);  // int4 base
    #pragma unroll 1
    for (int k = 0; k < TILE / 1024; ++k) {
        const int vi = v0 + k * 256 + tid;
        const bool okv = vi < NE / 4;
        int4 i4 = {0,0,0,0}, s4 = {0,0,0,0};
        if (okv) { i4 = ((const int4*)idx)[vi]; s4 = ((const int4*)sgn)[vi]; }
        const int g0 = vi * 4;
        #pragma unroll
        for (int m = 0; m < 4; ++m) {
            const int bucket = (m == 0) ? i4.x : (m == 1) ? i4.y : (m == 2) ? i4.z : i4.w;
            const int sg     = (m == 0) ? s4.x : (m == 1) ? s4.y : (m == 2) ? s4.z : s4.w;
            const int kb = okv ? (bucket >> 6) : 0;
            const int payload = (g0 + m) | ((bucket & 63) << 24)
                              | (int)((unsigned)sg & 0x80000000u);
            rank_and_stage(okv, kb, payload, cnt, stage, curA, listA, kb, (kb + 1) * CAPA);
        }
    }
    __syncthreads();
    flush_bins(cnt, basek, stage, curA, listA, 0, CAPA);
}

// ---------------- KB: fine split (bucket&63) ----------------
// grid 2048 = 64 parts x 32 tiles of 4096
__global__ __launch_bounds__(256, 5)
void pass_b_kernel(const int* __restrict__ curA, const int* __restrict__ listA,
                   int* __restrict__ curB, int* __restrict__ listB) {
    __shared__ int stage[64 * BINCAP];
    __shared__ int cnt[64];
    __shared__ int basek[64];
    const int tid  = threadIdx.x;
    const int part = blockIdx.x >> 5;
    const int tile = blockIdx.x & 31;
    if (tid < 64) cnt[tid] = 0;
    __syncthreads();

    const int pstart = part * CAPA;
    const int pcount = min(curA[part] - pstart, CAPA);
    const int t0 = tile * TILE;
    const int t1 = min(t0 + TILE, pcount);

    #pragma unroll 1
    for (int k = 0; k < TILE / 256; ++k) {
        const int i  = t0 + k * 256 + tid;
        const bool ok = i < t1;
        const int e  = ok ? listA[pstart + i] : 0;
        const int kb = ok ? ((e >> 24) & 63) : 0;
        const int payload = e & 0x807FFFFF;          // keep sign + g
        rank_and_stage(ok, kb, payload, cnt, stage, curB, listB,
                       part * 64 + kb, (part * 64 + kb + 1) * CAP);
    }
    __syncthreads();
    flush_bins(cnt, basek, stage, curB, listB, part * 64, CAP);
}

// ---------------- K4: transpose x[32][1e6] -> x_T[1e6][32] fp16 ----------------
__global__ __launch_bounds__(256, 4)
void transpose_kernel(const float* __restrict__ x, unsigned short* __restrict__ xT) {
    __shared__ float tile[32][257];
    const int tid = threadIdx.x;
    const int d0  = blockIdx.x * 256;
    const int row = tid >> 3;
    const int c8  = tid & 7;

    if (d0 + 256 <= D_TOTAL) {
        #pragma unroll
        for (int k = 0; k < 8; ++k) {
            const int c = (c8 + 8 * k) * 4;
            const float4 v = *(const float4*)(x + (size_t)row * D_TOTAL + d0 + c);
            tile[row][c] = v.x; tile[row][c+1] = v.y;
            tile[row][c+2] = v.z; tile[row][c+3] = v.w;
        }
    } else {
        for (int k = 0; k < 8; ++k) {
            const int c = (c8 + 8 * k) * 4;
            for (int m = 0; m < 4; ++m) {
                const int d = d0 + c + m;
                tile[row][c + m] = (d < D_TOTAL) ? x[(size_t)row * D_TOTAL + d] : 0.f;
            }
        }
    }
    __syncthreads();

    const int part = tid & 3;
    #pragma unroll
    for (int k = 0; k < 4; ++k) {
        const int dl = k * 64 + (tid >> 2);
        if (d0 + dl < D_TOTAL) {
            unsigned short h[8];
            #pragma unroll
            for (int i = 0; i < 8; ++i)
                h[i] = __half_as_ushort(__float2half(tile[part * 8 + i][dl]));
            *(uint4*)(xT + ((size_t)(d0 + dl)) * 32 + part * 8) = *(const uint4*)h;
        }
    }
}

// ---------------- K5: gather — 8-deep pipelined random loads ----------------
// block 256 = 4 waves. Lane: slot = lane>>2 (16 entry slots), bq = lane&3
// (batch octet). Per outer iter a wave covers 8 chunks of 16 entries.
__global__ __launch_bounds__(256, 8)
void gather_kernel(const int* __restrict__ curB, const int* __restrict__ listB,
                   const unsigned short* __restrict__ xT, float* __restrict__ out) {
    __shared__ int   lst[CAP];             // 9,216 B
    __shared__ float red[4][32];
    const int tid  = threadIdx.x;
    const int w    = tid >> 6;
    const int lane = tid & 63;
    const int p    = blockIdx.x;
    const int start = p * CAP;
    const int n     = min(curB[p] - start, CAP);
    const int slot = lane >> 2;
    const int bq   = lane & 3;

    // stage the bucket list in LDS (16B vectors + scalar tail)
    for (int i4 = tid; i4 < (n >> 2); i4 += 256)
        ((int4*)lst)[i4] = ((const int4*)(listB + start))[i4];
    if (tid < (n & 3)) lst[(n & ~3) + tid] = listB[start + (n & ~3) + tid];
    __syncthreads();

    float a0=0.f,a1=0.f,a2=0.f,a3=0.f,a4=0.f,a5=0.f,a6=0.f,a7=0.f;
    for (int base = w * 16; base < n; base += 512) {
        int pl[8];
        #pragma unroll
        for (int j = 0; j < 8; ++j) {
            const int e = base + j * 64 + slot;
            pl[j] = (e < n) ? lst[e] : 0;
        }
        uint4 hv[8];
        #pragma unroll
        for (int j = 0; j < 8; ++j) {
            int d = (pl[j] & 0x7FFFFF) >> 3;
            d = min(d, D_TOTAL - 1);                 // safety clamp for masked lanes
            hv[j] = *(const uint4*)(xT + (size_t)d * 32 + bq * 8);
        }
        #pragma unroll
        for (int j = 0; j < 8; ++j) {
            const int e = base + j * 64 + slot;
            const float s = (e < n) ? ((pl[j] < 0) ? -1.f : 1.f) : 0.f;
            float2 f;
            f = __half22float2(*(const __half2*)&hv[j].x); a0 = fmaf(s, f.x, a0); a1 = fmaf(s, f.y, a1);
            f = __half22float2(*(const __half2*)&hv[j].y); a2 = fmaf(s, f.x, a2); a3 = fmaf(s, f.y, a3);
            f = __half22float2(*(const __half2*)&hv[j].z); a4 = fmaf(s, f.x, a4); a5 = fmaf(s, f.y, a5);
            f = __half22float2(*(const __half2*)&hv[j].w); a6 = fmaf(s, f.x, a6); a7 = fmaf(s, f.y, a7);
        }
    }
    // reduce across the 16 slots (lane bits 2..5)
    #pragma unroll
    for (int m = 4; m <= 32; m <<= 1) {
        a0 += __shfl_xor(a0, m, 64); a1 += __shfl_xor(a1, m, 64);
        a2 += __shfl_xor(a2, m, 64); a3 += __shfl_xor(a3, m, 64);
        a4 += __shfl_xor(a4, m, 64); a5 += __shfl_xor(a5, m, 64);
        a6 += __shfl_xor(a6, m, 64); a7 += __shfl_xor(a7, m, 64);
    }
    if (lane < 4) {
        float* r = &red[w][lane * 8];
        r[0]=a0; r[1]=a1; r[2]=a2; r[3]=a3; r[4]=a4; r[5]=a5; r[6]=a6; r[7]=a7;
    }
    __syncthreads();
    if (tid < 32) {
        const float v = red[0][tid] + red[1][tid] + red[2][tid] + red[3][tid];
        out[(size_t)tid * PROJ + p] = v * SCALE;
    }
}

// ---------------- fallback (R1 kernel) if ws too small ----------------
#define BG 8
#define NCHUNK 64
#define BLOCK 1024
__global__ __launch_bounds__(BLOCK, 4)
void sjlt_scatter_fallback(const float* __restrict__ x,
                           const int* __restrict__ idx,
                           const int* __restrict__ sgn,
                           float* __restrict__ out) {
    __shared__ float acc[BG * PROJ];
    const int tid = threadIdx.x;
    #pragma unroll
    for (int i = 0; i < (BG * PROJ) / BLOCK; ++i) acc[i * BLOCK + tid] = 0.0f;
    __syncthreads();
    const int chunk = D_TOTAL / NCHUNK;
    const int d0 = blockIdx.x * chunk;
    const int d1 = d0 + chunk;
    const int bg = blockIdx.y * BG;
    for (int d = d0 + tid; d < d1; d += BLOCK) {
        const int4 i0 = *(const int4*)(idx + (size_t)d * C_SK);
        const int4 i1 = *(const int4*)(idx + (size_t)d * C_SK + 4);
        const int4 s0 = *(const int4*)(sgn + (size_t)d * C_SK);
        const int4 s1 = *(const int4*)(sgn + (size_t)d * C_SK + 4);
        #pragma unroll
        for (int b = 0; b < BG; ++b) {
            const float xv = __builtin_nontemporal_load(x + (size_t)(bg + b) * D_TOTAL + d);
            const unsigned xb = __float_as_uint(xv);
            float* accb = acc + b * PROJ;
            atomicAdd(accb + i0.x, __uint_as_float(xb ^ ((unsigned)s0.x & 0x80000000u)));
            atomicAdd(accb + i0.y, __uint_as_float(xb ^ ((unsigned)s0.y & 0x80000000u)));
            atomicAdd(accb + i0.z, __uint_as_float(xb ^ ((unsigned)s0.z & 0x80000000u)));
            atomicAdd(accb + i0.w, __uint_as_float(xb ^ ((unsigned)s0.w & 0x80000000u)));
            atomicAdd(accb + i1.x, __uint_as_float(xb ^ ((unsigned)s1.x & 0x80000000u)));
            atomicAdd(accb + i1.y, __uint_as_float(xb ^ ((unsigned)s1.y & 0x80000000u)));
            atomicAdd(accb + i1.z, __uint_as_float(xb ^ ((unsigned)s1.z & 0x80000000u)));
            atomicAdd(accb + i1.w, __uint_as_float(xb ^ ((unsigned)s1.w & 0x80000000u)));
        }
    }
    __syncthreads();
    #pragma unroll
    for (int i = 0; i < (BG * PROJ) / BLOCK; ++i) {
        const int lin = i * BLOCK + tid;
        const int b = lin >> 12;
        const int pp = lin & (PROJ - 1);
        unsafeAtomicAdd(out + (size_t)(bg + b) * PROJ + pp, acc[lin] * SCALE);
    }
}

extern "C" void kernel_launch(void* const* d_in, const int* in_sizes, int n_in,
                              void* d_out, int out_size, void* d_ws, size_t ws_size,
                              hipStream_t stream) {
    const float* x   = (const float*)d_in[0];
    const int*   idx = (const int*)d_in[1];
    const int*   sgn = (const int*)d_in[2];
    float*       out = (float*)d_out;

    if (ws_size < WS_NEEDED) {
        (void)hipMemsetAsync(out, 0, (size_t)out_size * sizeof(float), stream);
        dim3 grid(NCHUNK, 32 / BG);
        sjlt_scatter_fallback<<<grid, BLOCK, 0, stream>>>(x, idx, sgn, out);
        return;
    }

    char* ws = (char*)d_ws;
    int*            curA  = (int*)(ws + CURA_OFF);
    int*            curB  = (int*)(ws + CURB_OFF);
    int*            listB = (int*)(ws + LISTB_OFF);
    int*            listA = (int*)(ws + SHARED_OFF);
    unsigned short* xT    = (unsigned short*)(ws + SHARED_OFF);  // overlays listA

    init_cursors_kernel<<<(PROJ + 255) / 256, 256, 0, stream>>>(curA, curB);
    pass_a_kernel<<<(NE + TILE - 1) / TILE, 256, 0, stream>>>(idx, sgn, curA, listA);
    pass_b_kernel<<<64 * 32, 256, 0, stream>>>(curA, listA, curB, listB);
    transpose_kernel<<<(D_TOTAL + 255) / 256, 256, 0, stream>>>(x, xT);  // clobbers listA (dead)
    gather_kernel<<<PROJ, 256, 0, stream>>>(curB, listB, xT, out);
    // out fully overwritten by gather -> no memset needed
}

// Round 8
// 433.279 us; speedup vs baseline: 1.1613x; 1.0344x over previous
//
#include <hip/hip_runtime.h>
#include <hip/hip_fp16.h>

// SJLT projection: out[b, idx[d,j]] += x[b,d]*sgn[d,j]; out *= 1/sqrt(8)
// B=32, D=1e6, P=4096, c=8.
//
// R7 post-mortem: gather is at a hardware floor — 8M random 64B-line fetches
// = ~54 G lines/s (~3.3 TB/s) regardless of pipeline depth (R3/R5/R7 all
// 148-150 us). Remaining lever: prep serialization. R8 fuses the (independent)
// x-transpose into the pass_a dispatch with modulo-3 block interleave so the
// BW-bound transpose overlaps the LDS/ballot-bound coarse split. listA gets
// its own ws region (no xT alias) to make the overlap safe; serialized
// fallback path if ws is tight.

#define D_TOTAL 1000000
#define PROJ    4096
#define C_SK    8
#define NE      (D_TOTAL * C_SK)     // 8,000,000 entries
#define SCALE   0.35355339059327373f

#define CAPA    131072               // per coarse-partition cap (mu+17sig)
#define CAP     2304                 // per fine-bucket cap (mu+7.9sig)
#define BINCAP  112                  // per-tile per-bin LDS cap (mu=64,+6sig)
#define TILE    4096                 // entries per block in split passes
#define NBLK_A  ((NE + TILE - 1) / TILE)          // 1954
#define NBLK_T  ((D_TOTAL + 255) / 256)           // 3907

// ws layout (overlap-safe): cursors | listB | xT | listA
#define CURA_OFF   0                 // 64 ints
#define CURB_OFF   16384             // 4096 ints
#define LISTB_OFF  65536
#define LISTB_SZ   ((size_t)PROJ * CAP * 4)            // 37,748,736
#define XT_OFF     (LISTB_OFF + LISTB_SZ)              // 37,814,272
#define XT_SZ      ((size_t)D_TOTAL * 32 * 2)          // 64,000,000
#define LISTA_OFF  (XT_OFF + XT_SZ)                    // 101,814,272
#define LISTA_SZ   ((size_t)64 * CAPA * 4)             // 33,554,432
#define WS_ROOMY   (LISTA_OFF + LISTA_SZ)              // 135,368,704
#define WS_TIGHT   (XT_OFF + XT_SZ)                    // ~102 MB (listA aliases xT)

// ---------------- K0: init cursors ----------------
__global__ void init_cursors_kernel(int* __restrict__ curA, int* __restrict__ curB) {
    int i = blockIdx.x * blockDim.x + threadIdx.x;
    if (i < 64)   curA[i] = i * CAPA;
    if (i < PROJ) curB[i] = i * CAP;
}

// Ballot rank: leader lane does one LDS atomic per bin-group.
__device__ __forceinline__ void rank_and_stage(bool ok, int kb, int payload,
                                               int* __restrict__ cnt,
                                               int* __restrict__ stage,
                                               int* __restrict__ gcur,
                                               int* __restrict__ glist,
                                               int gcur_idx, int glim) {
    const unsigned long long valid = __ballot(ok);
    unsigned long long mask = valid;
    #pragma unroll
    for (int b = 0; b < 6; ++b) {
        const unsigned long long vote = __ballot((kb >> b) & 1);
        mask &= ((kb >> b) & 1) ? vote : ~vote;
    }
    if (ok) {
        const int lane = threadIdx.x & 63;
        const int rank = __popcll(mask & ((1ULL << lane) - 1ULL));
        const int leader = __ffsll((unsigned long long)mask) - 1;
        int base = 0;
        if (rank == 0) base = atomicAdd(&cnt[kb], __popcll(mask));
        base = __shfl(base, leader, 64);
        const int pos = base + rank;
        if (pos < BINCAP) {
            stage[kb * BINCAP + pos] = payload;
        } else {
            const int gp = atomicAdd(&gcur[gcur_idx], 1);
            if (gp < glim) glist[gp] = payload;
        }
    }
}

__device__ __forceinline__ void flush_bins(int* __restrict__ cnt,
                                           int* __restrict__ basek,
                                           const int* __restrict__ stage,
                                           int* __restrict__ gcur,
                                           int* __restrict__ glist,
                                           int gidx0, int capPer) {
    const int tid = threadIdx.x;
    if (tid < 64) {
        const int m = min(cnt[tid], BINCAP);
        cnt[tid]   = m;
        basek[tid] = atomicAdd(&gcur[gidx0 + tid], m);
    }
    __syncthreads();
    const int w = tid >> 6, lane = tid & 63;
    #pragma unroll 1
    for (int bi = 0; bi < 16; ++bi) {
        const int kb  = w * 16 + bi;
        const int m   = cnt[kb];
        const int gb  = basek[kb];
        const int lim = (gidx0 + kb + 1) * capPer;
        for (int i = lane; i < m; i += 64)
            if (gb + i < lim) glist[gb + i] = stage[kb * BINCAP + i];
    }
}

// ---------------- pass_a body (coarse split, bucket>>6) ----------------
__device__ __forceinline__ void pass_a_body(int abid, char* smem,
                                            const int* __restrict__ idx,
                                            const int* __restrict__ sgn,
                                            int* __restrict__ curA,
                                            int* __restrict__ listA) {
    int* stage = (int*)smem;                       // 28,672 B
    int* cnt   = (int*)(smem + 64 * BINCAP * 4);
    int* basek = cnt + 64;
    const int tid = threadIdx.x;
    if (tid < 64) cnt[tid] = 0;
    __syncthreads();

    const int v0 = abid * (TILE / 4);
    #pragma unroll 1
    for (int k = 0; k < TILE / 1024; ++k) {
        const int vi = v0 + k * 256 + tid;
        const bool okv = vi < NE / 4;
        int4 i4 = {0,0,0,0}, s4 = {0,0,0,0};
        if (okv) { i4 = ((const int4*)idx)[vi]; s4 = ((const int4*)sgn)[vi]; }
        const int g0 = vi * 4;
        #pragma unroll
        for (int m = 0; m < 4; ++m) {
            const int bucket = (m == 0) ? i4.x : (m == 1) ? i4.y : (m == 2) ? i4.z : i4.w;
            const int sg     = (m == 0) ? s4.x : (m == 1) ? s4.y : (m == 2) ? s4.z : s4.w;
            const int kb = okv ? (bucket >> 6) : 0;
            const int payload = (g0 + m) | ((bucket & 63) << 24)
                              | (int)((unsigned)sg & 0x80000000u);
            rank_and_stage(okv, kb, payload, cnt, stage, curA, listA, kb, (kb + 1) * CAPA);
        }
    }
    __syncthreads();
    flush_bins(cnt, basek, stage, curA, listA, 0, CAPA);
}

// ---------------- transpose body: x[32][1e6] -> x_T[1e6][32] fp16 ----------------
__device__ __forceinline__ void transpose_body(int tbid, char* smem,
                                               const float* __restrict__ x,
                                               unsigned short* __restrict__ xT) {
    float (*tile)[257] = (float(*)[257])smem;      // 32,896 B
    const int tid = threadIdx.x;
    const int d0  = tbid * 256;
    const int row = tid >> 3;
    const int c8  = tid & 7;

    if (d0 + 256 <= D_TOTAL) {
        #pragma unroll
        for (int k = 0; k < 8; ++k) {
            const int c = (c8 + 8 * k) * 4;
            const float4 v = *(const float4*)(x + (size_t)row * D_TOTAL + d0 + c);
            tile[row][c] = v.x; tile[row][c+1] = v.y;
            tile[row][c+2] = v.z; tile[row][c+3] = v.w;
        }
    } else {
        for (int k = 0; k < 8; ++k) {
            const int c = (c8 + 8 * k) * 4;
            for (int m = 0; m < 4; ++m) {
                const int d = d0 + c + m;
                tile[row][c + m] = (d < D_TOTAL) ? x[(size_t)row * D_TOTAL + d] : 0.f;
            }
        }
    }
    __syncthreads();

    const int part = tid & 3;
    #pragma unroll
    for (int k = 0; k < 4; ++k) {
        const int dl = k * 64 + (tid >> 2);
        if (d0 + dl < D_TOTAL) {
            unsigned short h[8];
            #pragma unroll
            for (int i = 0; i < 8; ++i)
                h[i] = __half_as_ushort(__float2half(tile[part * 8 + i][dl]));
            *(uint4*)(xT + ((size_t)(d0 + dl)) * 32 + part * 8) = *(const uint4*)h;
        }
    }
}

// ---------------- fused pass_a + transpose (roomy mode) ----------------
// grid = NBLK_A + NBLK_T = 5861. id%3==0 -> pass_a id/3; else transpose.
__global__ __launch_bounds__(256, 4)
void pass_a_transpose_kernel(const int* __restrict__ idx, const int* __restrict__ sgn,
                             int* __restrict__ curA, int* __restrict__ listA,
                             const float* __restrict__ x, unsigned short* __restrict__ xT) {
    __shared__ char smem[33024];
    const int id = blockIdx.x;
    if ((id % 3 == 0) && (id / 3 < NBLK_A)) {
        pass_a_body(id / 3, smem, idx, sgn, curA, listA);
    } else {
        const int tbid = id - id / 3 - ((id % 3) ? 1 : 0);
        if (tbid < NBLK_T) transpose_body(tbid, smem, x, xT);
    }
}

// ---------------- standalone kernels (tight mode) ----------------
__global__ __launch_bounds__(256, 5)
void pass_a_kernel(const int* __restrict__ idx, const int* __restrict__ sgn,
                   int* __restrict__ curA, int* __restrict__ listA) {
    __shared__ char smem[29184];
    pass_a_body(blockIdx.x, smem, idx, sgn, curA, listA);
}

__global__ __launch_bounds__(256, 4)
void transpose_kernel(const float* __restrict__ x, unsigned short* __restrict__ xT) {
    __shared__ char smem[32896];
    transpose_body(blockIdx.x, smem, x, xT);
}

// ---------------- KB: fine split (bucket&63) ----------------
__global__ __launch_bounds__(256, 5)
void pass_b_kernel(const int* __restrict__ curA, const int* __restrict__ listA,
                   int* __restrict__ curB, int* __restrict__ listB) {
    __shared__ int stage[64 * BINCAP];
    __shared__ int cnt[64];
    __shared__ int basek[64];
    const int tid  = threadIdx.x;
    const int part = blockIdx.x >> 5;
    const int tile = blockIdx.x & 31;
    if (tid < 64) cnt[tid] = 0;
    __syncthreads();

    const int pstart = part * CAPA;
    const int pcount = min(curA[part] - pstart, CAPA);
    const int t0 = tile * TILE;
    const int t1 = min(t0 + TILE, pcount);

    #pragma unroll 1
    for (int k = 0; k < TILE / 256; ++k) {
        const int i  = t0 + k * 256 + tid;
        const bool ok = i < t1;
        const int e  = ok ? listA[pstart + i] : 0;
        const int kb = ok ? ((e >> 24) & 63) : 0;
        const int payload = e & 0x807FFFFF;
        rank_and_stage(ok, kb, payload, cnt, stage, curB, listB,
                       part * 64 + kb, (part * 64 + kb + 1) * CAP);
    }
    __syncthreads();
    flush_bins(cnt, basek, stage, curB, listB, part * 64, CAP);
}

// ---------------- K5: gather ----------------
__global__ __launch_bounds__(256, 8)
void gather_kernel(const int* __restrict__ curB, const int* __restrict__ listB,
                   const unsigned short* __restrict__ xT, float* __restrict__ out) {
    __shared__ int   lst[CAP];
    __shared__ float red[4][32];
    const int tid  = threadIdx.x;
    const int w    = tid >> 6;
    const int lane = tid & 63;
    const int p    = blockIdx.x;
    const int start = p * CAP;
    const int n     = min(curB[p] - start, CAP);
    const int slot = lane >> 2;
    const int bq   = lane & 3;

    for (int i4 = tid; i4 < (n >> 2); i4 += 256)
        ((int4*)lst)[i4] = ((const int4*)(listB + start))[i4];
    if (tid < (n & 3)) lst[(n & ~3) + tid] = listB[start + (n & ~3) + tid];
    __syncthreads();

    float a0=0.f,a1=0.f,a2=0.f,a3=0.f,a4=0.f,a5=0.f,a6=0.f,a7=0.f;
    for (int base = w * 16; base < n; base += 512) {
        int pl[8];
        #pragma unroll
        for (int j = 0; j < 8; ++j) {
            const int e = base + j * 64 + slot;
            pl[j] = (e < n) ? lst[e] : 0;
        }
        uint4 hv[8];
        #pragma unroll
        for (int j = 0; j < 8; ++j) {
            int d = (pl[j] & 0x7FFFFF) >> 3;
            d = min(d, D_TOTAL - 1);
            hv[j] = *(const uint4*)(xT + (size_t)d * 32 + bq * 8);
        }
        #pragma unroll
        for (int j = 0; j < 8; ++j) {
            const int e = base + j * 64 + slot;
            const float s = (e < n) ? ((pl[j] < 0) ? -1.f : 1.f) : 0.f;
            float2 f;
            f = __half22float2(*(const __half2*)&hv[j].x); a0 = fmaf(s, f.x, a0); a1 = fmaf(s, f.y, a1);
            f = __half22float2(*(const __half2*)&hv[j].y); a2 = fmaf(s, f.x, a2); a3 = fmaf(s, f.y, a3);
            f = __half22float2(*(const __half2*)&hv[j].z); a4 = fmaf(s, f.x, a4); a5 = fmaf(s, f.y, a5);
            f = __half22float2(*(const __half2*)&hv[j].w); a6 = fmaf(s, f.x, a6); a7 = fmaf(s, f.y, a7);
        }
    }
    #pragma unroll
    for (int m = 4; m <= 32; m <<= 1) {
        a0 += __shfl_xor(a0, m, 64); a1 += __shfl_xor(a1, m, 64);
        a2 += __shfl_xor(a2, m, 64); a3 += __shfl_xor(a3, m, 64);
        a4 += __shfl_xor(a4, m, 64); a5 += __shfl_xor(a5, m, 64);
        a6 += __shfl_xor(a6, m, 64); a7 += __shfl_xor(a7, m, 64);
    }
    if (lane < 4) {
        float* r = &red[w][lane * 8];
        r[0]=a0; r[1]=a1; r[2]=a2; r[3]=a3; r[4]=a4; r[5]=a5; r[6]=a6; r[7]=a7;
    }
    __syncthreads();
    if (tid < 32) {
        const float v = red[0][tid] + red[1][tid] + red[2][tid] + red[3][tid];
        out[(size_t)tid * PROJ + p] = v * SCALE;
    }
}

// ---------------- fallback (R1 kernel) if ws too small ----------------
#define BG 8
#define NCHUNK 64
#define BLOCK 1024
__global__ __launch_bounds__(BLOCK, 4)
void sjlt_scatter_fallback(const float* __restrict__ x,
                           const int* __restrict__ idx,
                           const int* __restrict__ sgn,
                           float* __restrict__ out) {
    __shared__ float acc[BG * PROJ];
    const int tid = threadIdx.x;
    #pragma unroll
    for (int i = 0; i < (BG * PROJ) / BLOCK; ++i) acc[i * BLOCK + tid] = 0.0f;
    __syncthreads();
    const int chunk = D_TOTAL / NCHUNK;
    const int d0 = blockIdx.x * chunk;
    const int d1 = d0 + chunk;
    const int bg = blockIdx.y * BG;
    for (int d = d0 + tid; d < d1; d += BLOCK) {
        const int4 i0 = *(const int4*)(idx + (size_t)d * C_SK);
        const int4 i1 = *(const int4*)(idx + (size_t)d * C_SK + 4);
        const int4 s0 = *(const int4*)(sgn + (size_t)d * C_SK);
        const int4 s1 = *(const int4*)(sgn + (size_t)d * C_SK + 4);
        #pragma unroll
        for (int b = 0; b < BG; ++b) {
            const float xv = __builtin_nontemporal_load(x + (size_t)(bg + b) * D_TOTAL + d);
            const unsigned xb = __float_as_uint(xv);
            float* accb = acc + b * PROJ;
            atomicAdd(accb + i0.x, __uint_as_float(xb ^ ((unsigned)s0.x & 0x80000000u)));
            atomicAdd(accb + i0.y, __uint_as_float(xb ^ ((unsigned)s0.y & 0x80000000u)));
            atomicAdd(accb + i0.z, __uint_as_float(xb ^ ((unsigned)s0.z & 0x80000000u)));
            atomicAdd(accb + i0.w, __uint_as_float(xb ^ ((unsigned)s0.w & 0x80000000u)));
            atomicAdd(accb + i1.x, __uint_as_float(xb ^ ((unsigned)s1.x & 0x80000000u)));
            atomicAdd(accb + i1.y, __uint_as_float(xb ^ ((unsigned)s1.y & 0x80000000u)));
            atomicAdd(accb + i1.z, __uint_as_float(xb ^ ((unsigned)s1.z & 0x80000000u)));
            atomicAdd(accb + i1.w, __uint_as_float(xb ^ ((unsigned)s1.w & 0x80000000u)));
        }
    }
    __syncthreads();
    #pragma unroll
    for (int i = 0; i < (BG * PROJ) / BLOCK; ++i) {
        const int lin = i * BLOCK + tid;
        const int b = lin >> 12;
        const int pp = lin & (PROJ - 1);
        unsafeAtomicAdd(out + (size_t)(bg + b) * PROJ + pp, acc[lin] * SCALE);
    }
}

extern "C" void kernel_launch(void* const* d_in, const int* in_sizes, int n_in,
                              void* d_out, int out_size, void* d_ws, size_t ws_size,
                              hipStream_t stream) {
    const float* x   = (const float*)d_in[0];
    const int*   idx = (const int*)d_in[1];
    const int*   sgn = (const int*)d_in[2];
    float*       out = (float*)d_out;

    if (ws_size < WS_TIGHT) {
        (void)hipMemsetAsync(out, 0, (size_t)out_size * sizeof(float), stream);
        dim3 grid(NCHUNK, 32 / BG);
        sjlt_scatter_fallback<<<grid, BLOCK, 0, stream>>>(x, idx, sgn, out);
        return;
    }

    char* ws = (char*)d_ws;
    int*            curA  = (int*)(ws + CURA_OFF);
    int*            curB  = (int*)(ws + CURB_OFF);
    int*            listB = (int*)(ws + LISTB_OFF);
    unsigned short* xT    = (unsigned short*)(ws + XT_OFF);

    init_cursors_kernel<<<(PROJ + 255) / 256, 256, 0, stream>>>(curA, curB);

    if (ws_size >= WS_ROOMY) {
        // overlap-safe: listA in its own region; transpose runs concurrently
        int* listA = (int*)(ws + LISTA_OFF);
        pass_a_transpose_kernel<<<NBLK_A + NBLK_T, 256, 0, stream>>>(
            idx, sgn, curA, listA, x, xT);
        pass_b_kernel<<<64 * 32, 256, 0, stream>>>(curA, listA, curB, listB);
    } else {
        // tight: listA aliases xT region; serialize (R7 ordering)
        int* listA = (int*)(ws + XT_OFF);
        pass_a_kernel<<<NBLK_A, 256, 0, stream>>>(idx, sgn, curA, listA);
        pass_b_kernel<<<64 * 32, 256, 0, stream>>>(curA, listA, curB, listB);
        transpose_kernel<<<NBLK_T, 256, 0, stream>>>(x, xT);
    }
    gather_kernel<<<PROJ, 256, 0, stream>>>(curB, listB, xT, out);
}

// Round 9
// 358.646 us; speedup vs baseline: 1.4030x; 1.2081x over previous
//
#include <hip/hip_runtime.h>
#include <hip/hip_fp16.h>

// SJLT projection: out[b, idx[d,j]] += x[b,d]*sgn[d,j]; out *= 1/sqrt(8)
// B=32, D=1e6, P=4096, c=8.
//
// R8 post-mortem: gather bound by 8M random 64B L3->L2 fills (~54 G/s).
// Each xT line (one d) serves exactly c=8 entries, but bucket-major order
// scatters them across XCDs -> no L2 reuse. R9: partition by (d-segment,
// bucket); segment = 62500 d = 4 MB xT = one XCD L2. Gather blocks of
// segment s are pinned to XCD s%8 via the blockIdx%8 round-robin heuristic
// -> each line filled ~1x/XCD instead of 8x (fills 8M -> ~1M). Sort becomes
// segment-local (input is d-ordered, so segmentation is free in pass_a);
// gather emits per-(seg,bucket) 32-float partials; reduce sums 16 & scales.

#define D_TOTAL 1000000
#define PROJ    4096
#define C_SK    8
#define NE      (D_TOTAL * C_SK)     // 8,000,000 entries
#define SCALE   0.35355339059327373f

#define NSEG    16
#define SEG_D   62500                // d per segment (= 4 MB of xT)
#define CAPA2   8448                 // per-(seg,kb) cap (mu=7812, +7.2sig)
#define CAP_B   192                  // per-(seg,bucket) cap (mu=122, +6.3sig)
#define BINCAP_A 112                 // pass_a per-tile per-bin LDS cap
#define BINCAP_B 120                 // pass_b per-tile per-bin LDS cap
#define TILE    4096                 // pass_a tile (512 d)
#define TILE_B  4352                 // pass_b tile (17*256)
#define NBLK_A  ((NE + TILE - 1) / TILE)          // 1954
#define NBLK_T  ((D_TOTAL + 255) / 256)           // 3907

// ws layout (roomy): curA | curB | listB | xT | listA (partial overlays listA)
#define CURA_OFF    0                              // 1024 ints
#define CURB_OFF    16384                          // 65536 ints
#define LISTB_OFF   294912
#define LISTB_SZ    ((size_t)NSEG * PROJ * CAP_B * 4)   // 50,331,648
#define XT_OFF_R    (LISTB_OFF + LISTB_SZ)              // 50,626,560
#define XT_SZ       ((size_t)D_TOTAL * 32 * 2)          // 64,000,000
#define LISTA_OFF_R (XT_OFF_R + XT_SZ)                  // 114,626,560
#define LISTA_SZ    ((size_t)NSEG * 64 * CAPA2 * 4)     // 34,603,008
#define PARTIAL_SZ  ((size_t)NSEG * PROJ * 32 * 4)      // 8,388,608
#define WS_ROOMY    (LISTA_OFF_R + LISTA_SZ)            // 149,229,568
// tight layout: curA | curB | listB | partial | (xT == listA alias, serialized)
#define PARTIAL_T   (LISTB_OFF + LISTB_SZ)              // 50,626,560
#define XTA_OFF_T   (PARTIAL_T + PARTIAL_SZ)            // 59,015,168
#define WS_TIGHT    (XTA_OFF_T + XT_SZ)                 // 123,015,168

// ---------------- K0: init cursors ----------------
__global__ void init_cursors_kernel(int* __restrict__ curA, int* __restrict__ curB) {
    int i = blockIdx.x * blockDim.x + threadIdx.x;
    if (i < NSEG * 64) curA[i] = i * CAPA2;
    if (i < NSEG * PROJ) curB[i] = i * CAP_B;
}

// Ballot rank: leader lane does one LDS atomic per bin-group. kb in [0,64).
template<int BC>
__device__ __forceinline__ void rank_and_stage(bool ok, int kb, int payload,
                                               int* __restrict__ cnt,
                                               int* __restrict__ stage,
                                               int* __restrict__ gcur,
                                               int* __restrict__ glist,
                                               int gcur_idx, int glim) {
    const unsigned long long valid = __ballot(ok);
    unsigned long long mask = valid;
    #pragma unroll
    for (int b = 0; b < 6; ++b) {
        const unsigned long long vote = __ballot((kb >> b) & 1);
        mask &= ((kb >> b) & 1) ? vote : ~vote;
    }
    if (ok) {
        const int lane = threadIdx.x & 63;
        const int rank = __popcll(mask & ((1ULL << lane) - 1ULL));
        const int leader = __ffsll((unsigned long long)mask) - 1;
        int base = 0;
        if (rank == 0) base = atomicAdd(&cnt[kb], __popcll(mask));
        base = __shfl(base, leader, 64);
        const int pos = base + rank;
        if (pos < BC) {
            stage[kb * BC + pos] = payload;
        } else {
            const int gp = atomicAdd(&gcur[gcur_idx], 1);
            if (gp < glim) glist[gp] = payload;
        }
    }
}

template<int BC>
__device__ __forceinline__ void flush_bins(int* __restrict__ cnt,
                                           int* __restrict__ basek,
                                           const int* __restrict__ stage,
                                           int* __restrict__ gcur,
                                           int* __restrict__ glist,
                                           int gidx0, int capPer) {
    const int tid = threadIdx.x;
    if (tid < 64) {
        const int m = min(cnt[tid], BC);
        cnt[tid]   = m;
        basek[tid] = atomicAdd(&gcur[gidx0 + tid], m);
    }
    __syncthreads();
    const int w = tid >> 6, lane = tid & 63;
    #pragma unroll 1
    for (int bi = 0; bi < 16; ++bi) {
        const int kb  = w * 16 + bi;
        const int m   = cnt[kb];
        const int gb  = basek[kb];
        const int lim = (gidx0 + kb + 1) * capPer;
        for (int i = lane; i < m; i += 64)
            if (gb + i < lim) glist[gb + i] = stage[kb * BC + i];
    }
}

// ---------------- pass_a body: split by (seg, bucket>>6) ----------------
// payload {sign:31, low6:24..29, g:0..22}. Tile = 512 d -> one segment,
// except ~16 boundary tiles which take a per-entry direct-global slow path.
__device__ __forceinline__ void pass_a_body(int abid, char* smem,
                                            const int* __restrict__ idx,
                                            const int* __restrict__ sgn,
                                            int* __restrict__ curA,
                                            int* __restrict__ listA) {
    int* stage = (int*)smem;                       // 64*112*4 = 28,672 B
    int* cnt   = (int*)(smem + 64 * BINCAP_A * 4);
    int* basek = cnt + 64;
    const int tid = threadIdx.x;
    if (tid < 64) cnt[tid] = 0;
    __syncthreads();

    const int d_lo = abid * 512;
    const int seg  = d_lo / SEG_D;
    const bool boundary = ((d_lo + 511) / SEG_D) != seg;
    const int v0 = abid * (TILE / 4);

    #pragma unroll 1
    for (int k = 0; k < TILE / 1024; ++k) {
        const int vi = v0 + k * 256 + tid;
        const bool okv = vi < NE / 4;
        int4 i4 = {0,0,0,0}, s4 = {0,0,0,0};
        if (okv) { i4 = ((const int4*)idx)[vi]; s4 = ((const int4*)sgn)[vi]; }
        const int g0 = vi * 4;
        #pragma unroll
        for (int m = 0; m < 4; ++m) {
            const int bucket = (m == 0) ? i4.x : (m == 1) ? i4.y : (m == 2) ? i4.z : i4.w;
            const int sg     = (m == 0) ? s4.x : (m == 1) ? s4.y : (m == 2) ? s4.z : s4.w;
            const int kb = okv ? (bucket >> 6) : 0;
            const int payload = (g0 + m) | ((bucket & 63) << 24)
                              | (int)((unsigned)sg & 0x80000000u);
            if (!boundary) {
                rank_and_stage<BINCAP_A>(okv, kb, payload, cnt, stage, curA, listA,
                                         seg * 64 + kb, (seg * 64 + kb + 1) * CAPA2);
            } else if (okv) {                     // rare: per-entry direct
                const int segE = ((g0 + m) >> 3) / SEG_D;
                const int bin  = segE * 64 + kb;
                const int gp = atomicAdd(&curA[bin], 1);
                if (gp < (bin + 1) * CAPA2) listA[gp] = payload;
            }
        }
    }
    __syncthreads();
    flush_bins<BINCAP_A>(cnt, basek, stage, curA, listA, seg * 64, CAPA2);
}

// ---------------- transpose body: x[32][1e6] -> x_T[1e6][32] fp16 ----------------
__device__ __forceinline__ void transpose_body(int tbid, char* smem,
                                               const float* __restrict__ x,
                                               unsigned short* __restrict__ xT) {
    float (*tile)[257] = (float(*)[257])smem;      // 32,896 B
    const int tid = threadIdx.x;
    const int d0  = tbid * 256;
    const int row = tid >> 3;
    const int c8  = tid & 7;

    if (d0 + 256 <= D_TOTAL) {
        #pragma unroll
        for (int k = 0; k < 8; ++k) {
            const int c = (c8 + 8 * k) * 4;
            const float4 v = *(const float4*)(x + (size_t)row * D_TOTAL + d0 + c);
            tile[row][c] = v.x; tile[row][c+1] = v.y;
            tile[row][c+2] = v.z; tile[row][c+3] = v.w;
        }
    } else {
        for (int k = 0; k < 8; ++k) {
            const int c = (c8 + 8 * k) * 4;
            for (int m = 0; m < 4; ++m) {
                const int d = d0 + c + m;
                tile[row][c + m] = (d < D_TOTAL) ? x[(size_t)row * D_TOTAL + d] : 0.f;
            }
        }
    }
    __syncthreads();

    const int part = tid & 3;
    #pragma unroll
    for (int k = 0; k < 4; ++k) {
        const int dl = k * 64 + (tid >> 2);
        if (d0 + dl < D_TOTAL) {
            unsigned short h[8];
            #pragma unroll
            for (int i = 0; i < 8; ++i)
                h[i] = __half_as_ushort(__float2half(tile[part * 8 + i][dl]));
            *(uint4*)(xT + ((size_t)(d0 + dl)) * 32 + part * 8) = *(const uint4*)h;
        }
    }
}

// ---------------- fused pass_a + transpose (roomy) ----------------
__global__ __launch_bounds__(256, 4)
void pass_a_transpose_kernel(const int* __restrict__ idx, const int* __restrict__ sgn,
                             int* __restrict__ curA, int* __restrict__ listA,
                             const float* __restrict__ x, unsigned short* __restrict__ xT) {
    __shared__ char smem[33024];
    const int id = blockIdx.x;
    if ((id % 3 == 0) && (id / 3 < NBLK_A)) {
        pass_a_body(id / 3, smem, idx, sgn, curA, listA);
    } else {
        const int tbid = id - id / 3 - ((id % 3) ? 1 : 0);
        if (tbid < NBLK_T) transpose_body(tbid, smem, x, xT);
    }
}

// ---------------- standalone kernels (tight mode) ----------------
__global__ __launch_bounds__(256, 5)
void pass_a_kernel(const int* __restrict__ idx, const int* __restrict__ sgn,
                   int* __restrict__ curA, int* __restrict__ listA) {
    __shared__ char smem[29184];
    pass_a_body(blockIdx.x, smem, idx, sgn, curA, listA);
}

__global__ __launch_bounds__(256, 4)
void transpose_kernel(const float* __restrict__ x, unsigned short* __restrict__ xT) {
    __shared__ char smem[32896];
    transpose_body(blockIdx.x, smem, x, xT);
}

// ---------------- KB: fine split (bucket&63) within (seg,kb) ----------------
// grid 2048 = 1024 partitions x 2 tiles of 4352
__global__ __launch_bounds__(256, 5)
void pass_b_kernel(const int* __restrict__ curA, const int* __restrict__ listA,
                   int* __restrict__ curB, int* __restrict__ listB) {
    __shared__ int stage[64 * BINCAP_B];           // 30,720 B
    __shared__ int cnt[64];
    __shared__ int basek[64];
    const int tid  = threadIdx.x;
    const int part = blockIdx.x >> 1;
    const int tile = blockIdx.x & 1;
    if (tid < 64) cnt[tid] = 0;
    __syncthreads();

    const int pstart = part * CAPA2;
    const int pcount = min(curA[part] - pstart, CAPA2);
    const int t0 = tile * TILE_B;
    const int t1 = min(t0 + TILE_B, pcount);

    #pragma unroll 1
    for (int k = 0; k < TILE_B / 256; ++k) {
        const int i  = t0 + k * 256 + tid;
        const bool ok = i < t1;
        const int e  = ok ? listA[pstart + i] : 0;
        const int kb = ok ? ((e >> 24) & 63) : 0;
        const int payload = e & 0x807FFFFF;
        rank_and_stage<BINCAP_B>(ok, kb, payload, cnt, stage, curB, listB,
                                 part * 64 + kb, (part * 64 + kb + 1) * CAP_B);
    }
    __syncthreads();
    flush_bins<BINCAP_B>(cnt, basek, stage, curB, listB, part * 64, CAP_B);
}

// ---------------- K5: segmented gather -> partial[seg][p][32] ----------------
// grid 16384, block 256 = 4 waves, wave = one (seg, p). XCD affinity:
// gid&7 selects XCD (heuristic); seg = (gid&7) + 8*(j>>10) so each XCD's
// working set is one 4 MB xT segment at a time.
__global__ __launch_bounds__(256, 8)
void gather_seg_kernel(const int* __restrict__ curB, const int* __restrict__ listB,
                       const unsigned short* __restrict__ xT,
                       float* __restrict__ partial) {
    __shared__ int lst[4][CAP_B];                  // 3,072 B
    const int tid  = threadIdx.x;
    const int w    = tid >> 6;
    const int lane = tid & 63;
    const int gid  = blockIdx.x;
    const int k    = gid & 7;
    const int j    = gid >> 3;                     // [0, 2048)
    const int seg  = k + 8 * (j >> 10);
    const int p    = (j & 1023) * 4 + w;
    const int bin  = seg * PROJ + p;
    const int start = bin * CAP_B;
    const int n     = min(curB[bin] - start, CAP_B);

    for (int i = lane; i < n; i += 64) lst[w][i] = listB[start + i];

    const int slot = lane >> 2;                    // 16 entry slots
    const int bq   = lane & 3;                     // batch octet
    float a0=0.f,a1=0.f,a2=0.f,a3=0.f,a4=0.f,a5=0.f,a6=0.f,a7=0.f;
    #pragma unroll 2
    for (int base = 0; base < n; base += 16) {
        const int  e  = base + slot;
        const bool ok = e < n;
        const int  pl = lst[w][ok ? e : 0];
        int d = (pl & 0x7FFFFF) >> 3;
        d = min(d, D_TOTAL - 1);                   // clamp vs garbage when n==0
        const float s = ok ? ((pl < 0) ? -1.f : 1.f) : 0.f;
        const uint4 hv = *(const uint4*)(xT + (size_t)d * 32 + bq * 8);
        float2 f;
        f = __half22float2(*(const __half2*)&hv.x); a0 = fmaf(s, f.x, a0); a1 = fmaf(s, f.y, a1);
        f = __half22float2(*(const __half2*)&hv.y); a2 = fmaf(s, f.x, a2); a3 = fmaf(s, f.y, a3);
        f = __half22float2(*(const __half2*)&hv.z); a4 = fmaf(s, f.x, a4); a5 = fmaf(s, f.y, a5);
        f = __half22float2(*(const __half2*)&hv.w); a6 = fmaf(s, f.x, a6); a7 = fmaf(s, f.y, a7);
    }
    #pragma unroll
    for (int m = 4; m <= 32; m <<= 1) {
        a0 += __shfl_xor(a0, m, 64); a1 += __shfl_xor(a1, m, 64);
        a2 += __shfl_xor(a2, m, 64); a3 += __shfl_xor(a3, m, 64);
        a4 += __shfl_xor(a4, m, 64); a5 += __shfl_xor(a5, m, 64);
        a6 += __shfl_xor(a6, m, 64); a7 += __shfl_xor(a7, m, 64);
    }
    if (lane < 4) {
        float v[8] = {a0,a1,a2,a3,a4,a5,a6,a7};
        float* dst = partial + (size_t)bin * 32 + lane * 8;
        #pragma unroll
        for (int i = 0; i < 8; ++i) dst[i] = v[i];
    }
}

// ---------------- K6: reduce partials -> out ----------------
__global__ __launch_bounds__(256)
void reduce_kernel(const float* __restrict__ partial, float* __restrict__ out) {
    const int gtid = blockIdx.x * 256 + threadIdx.x;   // [0, 131072)
    const int p = gtid & (PROJ - 1);
    const int b = gtid >> 12;
    float s = 0.f;
    #pragma unroll
    for (int sg = 0; sg < NSEG; ++sg)
        s += partial[((size_t)(sg * PROJ + p)) * 32 + b];
    out[(size_t)b * PROJ + p] = s * SCALE;
}

// ---------------- fallback (R1 kernel) if ws too small ----------------
#define BG 8
#define NCHUNK 64
#define BLOCK 1024
__global__ __launch_bounds__(BLOCK, 4)
void sjlt_scatter_fallback(const float* __restrict__ x,
                           const int* __restrict__ idx,
                           const int* __restrict__ sgn,
                           float* __restrict__ out) {
    __shared__ float acc[BG * PROJ];
    const int tid = threadIdx.x;
    #pragma unroll
    for (int i = 0; i < (BG * PROJ) / BLOCK; ++i) acc[i * BLOCK + tid] = 0.0f;
    __syncthreads();
    const int chunk = D_TOTAL / NCHUNK;
    const int d0 = blockIdx.x * chunk;
    const int d1 = d0 + chunk;
    const int bg = blockIdx.y * BG;
    for (int d = d0 + tid; d < d1; d += BLOCK) {
        const int4 i0 = *(const int4*)(idx + (size_t)d * C_SK);
        const int4 i1 = *(const int4*)(idx + (size_t)d * C_SK + 4);
        const int4 s0 = *(const int4*)(sgn + (size_t)d * C_SK);
        const int4 s1 = *(const int4*)(sgn + (size_t)d * C_SK + 4);
        #pragma unroll
        for (int b = 0; b < BG; ++b) {
            const float xv = __builtin_nontemporal_load(x + (size_t)(bg + b) * D_TOTAL + d);
            const unsigned xb = __float_as_uint(xv);
            float* accb = acc + b * PROJ;
            atomicAdd(accb + i0.x, __uint_as_float(xb ^ ((unsigned)s0.x & 0x80000000u)));
            atomicAdd(accb + i0.y, __uint_as_float(xb ^ ((unsigned)s0.y & 0x80000000u)));
            atomicAdd(accb + i0.z, __uint_as_float(xb ^ ((unsigned)s0.z & 0x80000000u)));
            atomicAdd(accb + i0.w, __uint_as_float(xb ^ ((unsigned)s0.w & 0x80000000u)));
            atomicAdd(accb + i1.x, __uint_as_float(xb ^ ((unsigned)s1.x & 0x80000000u)));
            atomicAdd(accb + i1.y, __uint_as_float(xb ^ ((unsigned)s1.y & 0x80000000u)));
            atomicAdd(accb + i1.z, __uint_as_float(xb ^ ((unsigned)s1.z & 0x80000000u)));
            atomicAdd(accb + i1.w, __uint_as_float(xb ^ ((unsigned)s1.w & 0x80000000u)));
        }
    }
    __syncthreads();
    #pragma unroll
    for (int i = 0; i < (BG * PROJ) / BLOCK; ++i) {
        const int lin = i * BLOCK + tid;
        const int b = lin >> 12;
        const int pp = lin & (PROJ - 1);
        unsafeAtomicAdd(out + (size_t)(bg + b) * PROJ + pp, acc[lin] * SCALE);
    }
}

extern "C" void kernel_launch(void* const* d_in, const int* in_sizes, int n_in,
                              void* d_out, int out_size, void* d_ws, size_t ws_size,
                              hipStream_t stream) {
    const float* x   = (const float*)d_in[0];
    const int*   idx = (const int*)d_in[1];
    const int*   sgn = (const int*)d_in[2];
    float*       out = (float*)d_out;

    if (ws_size < WS_TIGHT) {
        (void)hipMemsetAsync(out, 0, (size_t)out_size * sizeof(float), stream);
        dim3 grid(NCHUNK, 32 / BG);
        sjlt_scatter_fallback<<<grid, BLOCK, 0, stream>>>(x, idx, sgn, out);
        return;
    }

    char* ws = (char*)d_ws;
    int* curA  = (int*)(ws + CURA_OFF);
    int* curB  = (int*)(ws + CURB_OFF);
    int* listB = (int*)(ws + LISTB_OFF);

    init_cursors_kernel<<<256, 256, 0, stream>>>(curA, curB);

    if (ws_size >= WS_ROOMY) {
        unsigned short* xT      = (unsigned short*)(ws + XT_OFF_R);
        int*            listA   = (int*)(ws + LISTA_OFF_R);
        float*          partial = (float*)(ws + LISTA_OFF_R);  // overlays dead listA
        pass_a_transpose_kernel<<<NBLK_A + NBLK_T, 256, 0, stream>>>(
            idx, sgn, curA, listA, x, xT);
        pass_b_kernel<<<2048, 256, 0, stream>>>(curA, listA, curB, listB);
        gather_seg_kernel<<<NSEG * PROJ / 4, 256, 0, stream>>>(curB, listB, xT, partial);
        reduce_kernel<<<(32 * PROJ) / 256, 256, 0, stream>>>(partial, out);
    } else {
        // tight: listA aliases xT; serialize transpose after pass_b
        float*          partial = (float*)(ws + PARTIAL_T);
        unsigned short* xT      = (unsigned short*)(ws + XTA_OFF_T);
        int*            listA   = (int*)(ws + XTA_OFF_T);
        pass_a_kernel<<<NBLK_A, 256, 0, stream>>>(idx, sgn, curA, listA);
        pass_b_kernel<<<2048, 256, 0, stream>>>(curA, listA, curB, listB);
        transpose_kernel<<<NBLK_T, 256, 0, stream>>>(x, xT);  // clobbers dead listA
        gather_seg_kernel<<<NSEG * PROJ / 4, 256, 0, stream>>>(curB, listB, xT, partial);
        reduce_kernel<<<(32 * PROJ) / 256, 256, 0, stream>>>(partial, out);
    }
}

// Round 10
// 357.884 us; speedup vs baseline: 1.4060x; 1.0021x over previous
//
#include <hip/hip_runtime.h>
#include <hip/hip_fp16.h>

// SJLT projection: out[b, idx[d,j]] += x[b,d]*sgn[d,j]; out *= 1/sqrt(8)
// B=32, D=1e6, P=4096, c=8.
//
// R9 post-mortem: segmented gather worked (gather off the top-5; xT L2-
// resident). New hot spot: fused pass_a+transpose 104 us, occupancy 36%,
// BW 23%, VALU 21% -> latency-bound rank chains at only 4 blocks/CU (33 KB
// LDS union). R10: cut LDS union to ~25 KB (fp16 transpose tile, BINCAP
// 112/120 -> 96) -> 6 blocks/CU for +50% latency hiding.

#define D_TOTAL 1000000
#define PROJ    4096
#define C_SK    8
#define NE      (D_TOTAL * C_SK)     // 8,000,000 entries
#define SCALE   0.35355339059327373f

#define NSEG    16
#define SEG_D   62500                // d per segment (= 4 MB of xT)
#define CAPA2   8448                 // per-(seg,kb) cap (mu=7812, +7.2sig)
#define CAP_B   192                  // per-(seg,bucket) cap (mu=122, +6.3sig)
#define BINCAP_A 96                  // pass_a per-tile per-bin LDS cap (mu=64,+4sig)
#define BINCAP_B 96                  // pass_b per-tile per-bin LDS cap (mu<=68,+3.4sig)
#define TILE    4096                 // pass_a tile (512 d)
#define TILE_B  4352                 // pass_b tile (17*256)
#define NBLK_A  ((NE + TILE - 1) / TILE)          // 1954
#define NBLK_T  ((D_TOTAL + 255) / 256)           // 3907

// smem: pass_a stage 64*96*4=24576 + cnt/basek 512 = 25088; transpose tile
// 32*260*2 = 16640 -> union 25088
#define SMEM_FUSED 25088

// ws layout (roomy): curA | curB | listB | xT | listA (partial overlays listA)
#define CURA_OFF    0                              // 1024 ints
#define CURB_OFF    16384                          // 65536 ints
#define LISTB_OFF   294912
#define LISTB_SZ    ((size_t)NSEG * PROJ * CAP_B * 4)   // 50,331,648
#define XT_OFF_R    (LISTB_OFF + LISTB_SZ)              // 50,626,560
#define XT_SZ       ((size_t)D_TOTAL * 32 * 2)          // 64,000,000
#define LISTA_OFF_R (XT_OFF_R + XT_SZ)                  // 114,626,560
#define LISTA_SZ    ((size_t)NSEG * 64 * CAPA2 * 4)     // 34,603,008
#define PARTIAL_SZ  ((size_t)NSEG * PROJ * 32 * 4)      // 8,388,608
#define WS_ROOMY    (LISTA_OFF_R + LISTA_SZ)            // 149,229,568
// tight layout: curA | curB | listB | partial | (xT == listA alias, serialized)
#define PARTIAL_T   (LISTB_OFF + LISTB_SZ)              // 50,626,560
#define XTA_OFF_T   (PARTIAL_T + PARTIAL_SZ)            // 59,015,168
#define WS_TIGHT    (XTA_OFF_T + XT_SZ)                 // 123,015,168

// ---------------- K0: init cursors ----------------
__global__ void init_cursors_kernel(int* __restrict__ curA, int* __restrict__ curB) {
    int i = blockIdx.x * blockDim.x + threadIdx.x;
    if (i < NSEG * 64) curA[i] = i * CAPA2;
    if (i < NSEG * PROJ) curB[i] = i * CAP_B;
}

// Ballot rank: leader lane does one LDS atomic per bin-group. kb in [0,64).
template<int BC>
__device__ __forceinline__ void rank_and_stage(bool ok, int kb, int payload,
                                               int* __restrict__ cnt,
                                               int* __restrict__ stage,
                                               int* __restrict__ gcur,
                                               int* __restrict__ glist,
                                               int gcur_idx, int glim) {
    const unsigned long long valid = __ballot(ok);
    unsigned long long mask = valid;
    #pragma unroll
    for (int b = 0; b < 6; ++b) {
        const unsigned long long vote = __ballot((kb >> b) & 1);
        mask &= ((kb >> b) & 1) ? vote : ~vote;
    }
    if (ok) {
        const int lane = threadIdx.x & 63;
        const int rank = __popcll(mask & ((1ULL << lane) - 1ULL));
        const int leader = __ffsll((unsigned long long)mask) - 1;
        int base = 0;
        if (rank == 0) base = atomicAdd(&cnt[kb], __popcll(mask));
        base = __shfl(base, leader, 64);
        const int pos = base + rank;
        if (pos < BC) {
            stage[kb * BC + pos] = payload;
        } else {
            const int gp = atomicAdd(&gcur[gcur_idx], 1);
            if (gp < glim) glist[gp] = payload;
        }
    }
}

template<int BC>
__device__ __forceinline__ void flush_bins(int* __restrict__ cnt,
                                           int* __restrict__ basek,
                                           const int* __restrict__ stage,
                                           int* __restrict__ gcur,
                                           int* __restrict__ glist,
                                           int gidx0, int capPer) {
    const int tid = threadIdx.x;
    if (tid < 64) {
        const int m = min(cnt[tid], BC);
        cnt[tid]   = m;
        basek[tid] = atomicAdd(&gcur[gidx0 + tid], m);
    }
    __syncthreads();
    const int w = tid >> 6, lane = tid & 63;
    #pragma unroll 1
    for (int bi = 0; bi < 16; ++bi) {
        const int kb  = w * 16 + bi;
        const int m   = cnt[kb];
        const int gb  = basek[kb];
        const int lim = (gidx0 + kb + 1) * capPer;
        for (int i = lane; i < m; i += 64)
            if (gb + i < lim) glist[gb + i] = stage[kb * BC + i];
    }
}

// ---------------- pass_a body: split by (seg, bucket>>6) ----------------
// payload {sign:31, low6:24..29, g:0..22}. Tile = 512 d -> one segment,
// except ~16 boundary tiles which take a per-entry direct-global slow path.
__device__ __forceinline__ void pass_a_body(int abid, char* smem,
                                            const int* __restrict__ idx,
                                            const int* __restrict__ sgn,
                                            int* __restrict__ curA,
                                            int* __restrict__ listA) {
    int* stage = (int*)smem;                       // 64*96*4 = 24,576 B
    int* cnt   = (int*)(smem + 64 * BINCAP_A * 4);
    int* basek = cnt + 64;
    const int tid = threadIdx.x;
    if (tid < 64) cnt[tid] = 0;
    __syncthreads();

    const int d_lo = abid * 512;
    const int seg  = d_lo / SEG_D;
    const bool boundary = ((d_lo + 511) / SEG_D) != seg;
    const int v0 = abid * (TILE / 4);

    #pragma unroll 1
    for (int k = 0; k < TILE / 1024; ++k) {
        const int vi = v0 + k * 256 + tid;
        const bool okv = vi < NE / 4;
        int4 i4 = {0,0,0,0}, s4 = {0,0,0,0};
        if (okv) { i4 = ((const int4*)idx)[vi]; s4 = ((const int4*)sgn)[vi]; }
        const int g0 = vi * 4;
        #pragma unroll
        for (int m = 0; m < 4; ++m) {
            const int bucket = (m == 0) ? i4.x : (m == 1) ? i4.y : (m == 2) ? i4.z : i4.w;
            const int sg     = (m == 0) ? s4.x : (m == 1) ? s4.y : (m == 2) ? s4.z : s4.w;
            const int kb = okv ? (bucket >> 6) : 0;
            const int payload = (g0 + m) | ((bucket & 63) << 24)
                              | (int)((unsigned)sg & 0x80000000u);
            if (!boundary) {
                rank_and_stage<BINCAP_A>(okv, kb, payload, cnt, stage, curA, listA,
                                         seg * 64 + kb, (seg * 64 + kb + 1) * CAPA2);
            } else if (okv) {                     // rare: per-entry direct
                const int segE = ((g0 + m) >> 3) / SEG_D;
                const int bin  = segE * 64 + kb;
                const int gp = atomicAdd(&curA[bin], 1);
                if (gp < (bin + 1) * CAPA2) listA[gp] = payload;
            }
        }
    }
    __syncthreads();
    flush_bins<BINCAP_A>(cnt, basek, stage, curA, listA, seg * 64, CAPA2);
}

// ---------------- transpose body: x[32][1e6] -> x_T[1e6][32] fp16 ----------------
// LDS tile is fp16 (ushort[32][260]; stride 260 keeps 8B writes aligned).
__device__ __forceinline__ void transpose_body(int tbid, char* smem,
                                               const float* __restrict__ x,
                                               unsigned short* __restrict__ xT) {
    unsigned short (*tile)[260] = (unsigned short(*)[260])smem;  // 16,640 B
    const int tid = threadIdx.x;
    const int d0  = tbid * 256;
    const int row = tid >> 3;
    const int c8  = tid & 7;

    if (d0 + 256 <= D_TOTAL) {
        #pragma unroll
        for (int k = 0; k < 8; ++k) {
            const int c = (c8 + 8 * k) * 4;
            const float4 v = *(const float4*)(x + (size_t)row * D_TOTAL + d0 + c);
            unsigned short h[4];
            h[0] = __half_as_ushort(__float2half(v.x));
            h[1] = __half_as_ushort(__float2half(v.y));
            h[2] = __half_as_ushort(__float2half(v.z));
            h[3] = __half_as_ushort(__float2half(v.w));
            *(uint2*)&tile[row][c] = *(const uint2*)h;
        }
    } else {
        for (int k = 0; k < 8; ++k) {
            const int c = (c8 + 8 * k) * 4;
            for (int m = 0; m < 4; ++m) {
                const int d = d0 + c + m;
                tile[row][c + m] = __half_as_ushort(
                    __float2half((d < D_TOTAL) ? x[(size_t)row * D_TOTAL + d] : 0.f));
            }
        }
    }
    __syncthreads();

    const int part = tid & 3;
    #pragma unroll
    for (int k = 0; k < 4; ++k) {
        const int dl = k * 64 + (tid >> 2);
        if (d0 + dl < D_TOTAL) {
            unsigned short h[8];
            #pragma unroll
            for (int i = 0; i < 8; ++i)
                h[i] = tile[part * 8 + i][dl];
            *(uint4*)(xT + ((size_t)(d0 + dl)) * 32 + part * 8) = *(const uint4*)h;
        }
    }
}

// ---------------- fused pass_a + transpose (roomy) ----------------
__global__ __launch_bounds__(256, 6)
void pass_a_transpose_kernel(const int* __restrict__ idx, const int* __restrict__ sgn,
                             int* __restrict__ curA, int* __restrict__ listA,
                             const float* __restrict__ x, unsigned short* __restrict__ xT) {
    __shared__ char smem[SMEM_FUSED];
    const int id = blockIdx.x;
    if ((id % 3 == 0) && (id / 3 < NBLK_A)) {
        pass_a_body(id / 3, smem, idx, sgn, curA, listA);
    } else {
        const int tbid = id - id / 3 - ((id % 3) ? 1 : 0);
        if (tbid < NBLK_T) transpose_body(tbid, smem, x, xT);
    }
}

// ---------------- standalone kernels (tight mode) ----------------
__global__ __launch_bounds__(256, 6)
void pass_a_kernel(const int* __restrict__ idx, const int* __restrict__ sgn,
                   int* __restrict__ curA, int* __restrict__ listA) {
    __shared__ char smem[SMEM_FUSED];
    pass_a_body(blockIdx.x, smem, idx, sgn, curA, listA);
}

__global__ __launch_bounds__(256, 6)
void transpose_kernel(const float* __restrict__ x, unsigned short* __restrict__ xT) {
    __shared__ char smem[16640];
    transpose_body(blockIdx.x, smem, x, xT);
}

// ---------------- KB: fine split (bucket&63) within (seg,kb) ----------------
// grid 2048 = 1024 partitions x 2 tiles of 4352
__global__ __launch_bounds__(256, 6)
void pass_b_kernel(const int* __restrict__ curA, const int* __restrict__ listA,
                   int* __restrict__ curB, int* __restrict__ listB) {
    __shared__ int stage[64 * BINCAP_B];           // 24,576 B
    __shared__ int cnt[64];
    __shared__ int basek[64];
    const int tid  = threadIdx.x;
    const int part = blockIdx.x >> 1;
    const int tile = blockIdx.x & 1;
    if (tid < 64) cnt[tid] = 0;
    __syncthreads();

    const int pstart = part * CAPA2;
    const int pcount = min(curA[part] - pstart, CAPA2);
    const int t0 = tile * TILE_B;
    const int t1 = min(t0 + TILE_B, pcount);

    #pragma unroll 1
    for (int k = 0; k < TILE_B / 256; ++k) {
        const int i  = t0 + k * 256 + tid;
        const bool ok = i < t1;
        const int e  = ok ? listA[pstart + i] : 0;
        const int kb = ok ? ((e >> 24) & 63) : 0;
        const int payload = e & 0x807FFFFF;
        rank_and_stage<BINCAP_B>(ok, kb, payload, cnt, stage, curB, listB,
                                 part * 64 + kb, (part * 64 + kb + 1) * CAP_B);
    }
    __syncthreads();
    flush_bins<BINCAP_B>(cnt, basek, stage, curB, listB, part * 64, CAP_B);
}

// ---------------- K5: segmented gather -> partial[seg][p][32] ----------------
// grid 16384, block 256 = 4 waves, wave = one (seg, p). XCD affinity:
// gid&7 selects XCD (heuristic); seg = (gid&7) + 8*(j>>10) so each XCD's
// working set is one 4 MB xT segment at a time.
__global__ __launch_bounds__(256, 8)
void gather_seg_kernel(const int* __restrict__ curB, const int* __restrict__ listB,
                       const unsigned short* __restrict__ xT,
                       float* __restrict__ partial) {
    __shared__ int lst[4][CAP_B];                  // 3,072 B
    const int tid  = threadIdx.x;
    const int w    = tid >> 6;
    const int lane = tid & 63;
    const int gid  = blockIdx.x;
    const int k    = gid & 7;
    const int j    = gid >> 3;                     // [0, 2048)
    const int seg  = k + 8 * (j >> 10);
    const int p    = (j & 1023) * 4 + w;
    const int bin  = seg * PROJ + p;
    const int start = bin * CAP_B;
    const int n     = min(curB[bin] - start, CAP_B);

    for (int i = lane; i < n; i += 64) lst[w][i] = listB[start + i];

    const int slot = lane >> 2;                    // 16 entry slots
    const int bq   = lane & 3;                     // batch octet
    float a0=0.f,a1=0.f,a2=0.f,a3=0.f,a4=0.f,a5=0.f,a6=0.f,a7=0.f;
    #pragma unroll 2
    for (int base = 0; base < n; base += 16) {
        const int  e  = base + slot;
        const bool ok = e < n;
        const int  pl = lst[w][ok ? e : 0];
        int d = (pl & 0x7FFFFF) >> 3;
        d = min(d, D_TOTAL - 1);                   // clamp vs garbage when n==0
        const float s = ok ? ((pl < 0) ? -1.f : 1.f) : 0.f;
        const uint4 hv = *(const uint4*)(xT + (size_t)d * 32 + bq * 8);
        float2 f;
        f = __half22float2(*(const __half2*)&hv.x); a0 = fmaf(s, f.x, a0); a1 = fmaf(s, f.y, a1);
        f = __half22float2(*(const __half2*)&hv.y); a2 = fmaf(s, f.x, a2); a3 = fmaf(s, f.y, a3);
        f = __half22float2(*(const __half2*)&hv.z); a4 = fmaf(s, f.x, a4); a5 = fmaf(s, f.y, a5);
        f = __half22float2(*(const __half2*)&hv.w); a6 = fmaf(s, f.x, a6); a7 = fmaf(s, f.y, a7);
    }
    #pragma unroll
    for (int m = 4; m <= 32; m <<= 1) {
        a0 += __shfl_xor(a0, m, 64); a1 += __shfl_xor(a1, m, 64);
        a2 += __shfl_xor(a2, m, 64); a3 += __shfl_xor(a3, m, 64);
        a4 += __shfl_xor(a4, m, 64); a5 += __shfl_xor(a5, m, 64);
        a6 += __shfl_xor(a6, m, 64); a7 += __shfl_xor(a7, m, 64);
    }
    if (lane < 4) {
        float v[8] = {a0,a1,a2,a3,a4,a5,a6,a7};
        float* dst = partial + (size_t)bin * 32 + lane * 8;
        #pragma unroll
        for (int i = 0; i < 8; ++i) dst[i] = v[i];
    }
}

// ---------------- K6: reduce partials -> out ----------------
__global__ __launch_bounds__(256)
void reduce_kernel(const float* __restrict__ partial, float* __restrict__ out) {
    const int gtid = blockIdx.x * 256 + threadIdx.x;   // [0, 131072)
    const int p = gtid & (PROJ - 1);
    const int b = gtid >> 12;
    float s = 0.f;
    #pragma unroll
    for (int sg = 0; sg < NSEG; ++sg)
        s += partial[((size_t)(sg * PROJ + p)) * 32 + b];
    out[(size_t)b * PROJ + p] = s * SCALE;
}

// ---------------- fallback (R1 kernel) if ws too small ----------------
#define BG 8
#define NCHUNK 64
#define BLOCK 1024
__global__ __launch_bounds__(BLOCK, 4)
void sjlt_scatter_fallback(const float* __restrict__ x,
                           const int* __restrict__ idx,
                           const int* __restrict__ sgn,
                           float* __restrict__ out) {
    __shared__ float acc[BG * PROJ];
    const int tid = threadIdx.x;
    #pragma unroll
    for (int i = 0; i < (BG * PROJ) / BLOCK; ++i) acc[i * BLOCK + tid] = 0.0f;
    __syncthreads();
    const int chunk = D_TOTAL / NCHUNK;
    const int d0 = blockIdx.x * chunk;
    const int d1 = d0 + chunk;
    const int bg = blockIdx.y * BG;
    for (int d = d0 + tid; d < d1; d += BLOCK) {
        const int4 i0 = *(const int4*)(idx + (size_t)d * C_SK);
        const int4 i1 = *(const int4*)(idx + (size_t)d * C_SK + 4);
        const int4 s0 = *(const int4*)(sgn + (size_t)d * C_SK);
        const int4 s1 = *(const int4*)(sgn + (size_t)d * C_SK + 4);
        #pragma unroll
        for (int b = 0; b < BG; ++b) {
            const float xv = __builtin_nontemporal_load(x + (size_t)(bg + b) * D_TOTAL + d);
            const unsigned xb = __float_as_uint(xv);
            float* accb = acc + b * PROJ;
            atomicAdd(accb + i0.x, __uint_as_float(xb ^ ((unsigned)s0.x & 0x80000000u)));
            atomicAdd(accb + i0.y, __uint_as_float(xb ^ ((unsigned)s0.y & 0x80000000u)));
            atomicAdd(accb + i0.z, __uint_as_float(xb ^ ((unsigned)s0.z & 0x80000000u)));
            atomicAdd(accb + i0.w, __uint_as_float(xb ^ ((unsigned)s0.w & 0x80000000u)));
            atomicAdd(accb + i1.x, __uint_as_float(xb ^ ((unsigned)s1.x & 0x80000000u)));
            atomicAdd(accb + i1.y, __uint_as_float(xb ^ ((unsigned)s1.y & 0x80000000u)));
            atomicAdd(accb + i1.z, __uint_as_float(xb ^ ((unsigned)s1.z & 0x80000000u)));
            atomicAdd(accb + i1.w, __uint_as_float(xb ^ ((unsigned)s1.w & 0x80000000u)));
        }
    }
    __syncthreads();
    #pragma unroll
    for (int i = 0; i < (BG * PROJ) / BLOCK; ++i) {
        const int lin = i * BLOCK + tid;
        const int b = lin >> 12;
        const int pp = lin & (PROJ - 1);
        unsafeAtomicAdd(out + (size_t)(bg + b) * PROJ + pp, acc[lin] * SCALE);
    }
}

extern "C" void kernel_launch(void* const* d_in, const int* in_sizes, int n_in,
                              void* d_out, int out_size, void* d_ws, size_t ws_size,
                              hipStream_t stream) {
    const float* x   = (const float*)d_in[0];
    const int*   idx = (const int*)d_in[1];
    const int*   sgn = (const int*)d_in[2];
    float*       out = (float*)d_out;

    if (ws_size < WS_TIGHT) {
        (void)hipMemsetAsync(out, 0, (size_t)out_size * sizeof(float), stream);
        dim3 grid(NCHUNK, 32 / BG);
        sjlt_scatter_fallback<<<grid, BLOCK, 0, stream>>>(x, idx, sgn, out);
        return;
    }

    char* ws = (char*)d_ws;
    int* curA  = (int*)(ws + CURA_OFF);
    int* curB  = (int*)(ws + CURB_OFF);
    int* listB = (int*)(ws + LISTB_OFF);

    init_cursors_kernel<<<256, 256, 0, stream>>>(curA, curB);

    if (ws_size >= WS_ROOMY) {
        unsigned short* xT      = (unsigned short*)(ws + XT_OFF_R);
        int*            listA   = (int*)(ws + LISTA_OFF_R);
        float*          partial = (float*)(ws + LISTA_OFF_R);  // overlays dead listA
        pass_a_transpose_kernel<<<NBLK_A + NBLK_T, 256, 0, stream>>>(
            idx, sgn, curA, listA, x, xT);
        pass_b_kernel<<<2048, 256, 0, stream>>>(curA, listA, curB, listB);
        gather_seg_kernel<<<NSEG * PROJ / 4, 256, 0, stream>>>(curB, listB, xT, partial);
        reduce_kernel<<<(32 * PROJ) / 256, 256, 0, stream>>>(partial, out);
    } else {
        // tight: listA aliases xT; serialize transpose after pass_b
        float*          partial = (float*)(ws + PARTIAL_T);
        unsigned short* xT      = (unsigned short*)(ws + XTA_OFF_T);
        int*            listA   = (int*)(ws + XTA_OFF_T);
        pass_a_kernel<<<NBLK_A, 256, 0, stream>>>(idx, sgn, curA, listA);
        pass_b_kernel<<<2048, 256, 0, stream>>>(curA, listA, curB, listB);
        transpose_kernel<<<NBLK_T, 256, 0, stream>>>(x, xT);  // clobbers dead listA
        gather_seg_kernel<<<NSEG * PROJ / 4, 256, 0, stream>>>(curB, listB, xT, partial);
        reduce_kernel<<<(32 * PROJ) / 256, 256, 0, stream>>>(partial, out);
    }
}